// Round 3
// baseline (792.851 us; speedup 1.0000x reference)
//
#include <hip/hip_runtime.h>

namespace {
constexpr int D_  = 4;
constexpr int ND  = 9;     // 2D+1
constexpr int NK  = 81;
constexpr int B_  = 4, C_ = 64, H_ = 192, W_ = 448;

constexpr int TH  = 16;    // output rows per block
constexpr int TXN = 16;    // threads along x
constexpr int PX  = 4;     // pixels per thread along x
constexpr int TW  = TXN * PX;          // 64
constexpr int CCH = 8;                 // channels staged per round
constexpr int HC  = TW + 2 * D_;       // 72 halo cols
constexpr int HCP = 76;                // padded LDS row stride
constexpr int NTH = TH * TXN;          // 256
constexpr int ROUNDS = C_ / CCH;       // 8
constexpr int PLANE  = H_ * W_;        // 86016

constexpr int NTX  = W_ / TW;          // 7
constexpr int NTY  = H_ / TH;          // 12
constexpr int NWG  = NTX * ND * NTY * B_;   // 3024
constexpr int NXCD = 8;
constexpr int CHUNK = NWG / NXCD;      // 378 (exact; 378 % 9 == 0 -> tile groups never straddle)
static_assert(CHUNK * NXCD == NWG, "bijective chunked swizzle");
}

__global__ __launch_bounds__(NTH, 4)
void corr81_kernel(const float* __restrict__ f1, const float* __restrict__ f2,
                   float* __restrict__ out)
{
    __shared__ float s2[CCH * TH * HCP];   // 38912 B -> 4 blocks/CU

    const int tid = threadIdx.x;
    const int tx  = tid & (TXN - 1);
    const int ty  = tid >> 4;

    // ---- T1: XCD-chunked swizzle (dispatch is round-robin over 8 XCDs) ----
    const int bid = blockIdx.x;
    const int wg  = (bid & (NXCD - 1)) * CHUNK + (bid >> 3);
    // logical order: g fastest, then tilex, then ytile, then b
    const int g   = wg % ND;
    const int t1  = wg / ND;
    const int tilex = t1 % NTX;
    const int t2  = t1 / NTX;
    const int yt  = t2 % NTY;
    const int b   = t2 / NTY;

    const int x0 = tilex * TW;
    const int y0 = yt * TH;
    const int gx = x0 + tx * PX;
    const int gy = y0 + ty;

    // ---- staging geometry: thread owns 9 contiguous f4 chunks of one (c,row) ----
    const int half = tid & 1;              // which half of the 72-col row
    const int pair = tid >> 1;             // 0..127
    const int sc   = pair >> 4;            // channel 0..7
    const int sr   = pair & 15;            // staged row 0..15
    const int syy  = y0 + g - D_ + sr;     // feat2 source row
    const bool okY = (syy >= 0) && (syy < H_);
    const int  syc = syy < 0 ? 0 : (syy >= H_ - 1 ? H_ - 1 : syy);
    const int  sxb = x0 - D_ + 36 * half;  // first col of this thread's 9 chunks (16B-aligned)

    bool sok[9];
#pragma unroll
    for (int i = 0; i < 9; ++i) {
        int xx = sxb + 4 * i;
        sok[i] = okY && (xx >= 0) && (xx + 4 <= W_);   // chunks are fully in or fully out
    }
    const float* f2r = f2 + ((size_t)(b * C_ + sc) * H_ + syc) * W_ + sxb;
    float* const sw  = s2 + (sc * TH + sr) * HCP + 36 * half;

    // ---- prologue: issue round 0 loads ----
    float4 v[9];
#pragma unroll
    for (int i = 0; i < 9; ++i) {
        float4 t = make_float4(0.f, 0.f, 0.f, 0.f);
        if (sok[i]) t = *(const float4*)(f2r + 4 * i);
        v[i] = t;
    }

    float acc[ND][PX];
#pragma unroll
    for (int dx = 0; dx < ND; ++dx)
#pragma unroll
        for (int p = 0; p < PX; ++p) acc[dx][p] = 0.f;

    const float* f1q   = f1 + ((size_t)(b * C_) * H_ + gy) * W_ + gx;
    const float* sbase = s2 + ty * HCP + 4 * tx;

    for (int rr = 0; rr < ROUNDS; ++rr) {
        __syncthreads();                   // previous round's LDS reads done

        // ---- write-late: prefetched regs -> LDS ----
#pragma unroll
        for (int i = 0; i < 9; ++i)
            *(float4*)(sw + 4 * i) = v[i];
        __syncthreads();                   // staged data visible

        // ---- issue-early: next round's global loads (land during compute) ----
        if (rr + 1 < ROUNDS) {
            const size_t coff = (size_t)(rr + 1) * CCH * PLANE;
#pragma unroll
            for (int i = 0; i < 9; ++i) {
                float4 t = make_float4(0.f, 0.f, 0.f, 0.f);
                if (sok[i]) t = *(const float4*)(f2r + coff + 4 * i);
                v[i] = t;
            }
        }

        // ---- compute: 8 channels x 9 dx x 4 px ----
        const size_t c0 = (size_t)rr * CCH * PLANE;
#pragma unroll
        for (int c = 0; c < CCH; ++c) {
            float4 af = *(const float4*)(f1q + c0 + (size_t)c * PLANE);
            float a_[PX] = {af.x, af.y, af.z, af.w};
            const float* rp = sbase + c * (TH * HCP);
            float r_[12];
            *(float4*)&r_[0] = *(const float4*)(rp);
            *(float4*)&r_[4] = *(const float4*)(rp + 4);
            *(float4*)&r_[8] = *(const float4*)(rp + 8);
#pragma unroll
            for (int dx = 0; dx < ND; ++dx)
#pragma unroll
                for (int p = 0; p < PX; ++p)
                    acc[dx][p] = fmaf(a_[p], r_[p + dx], acc[dx][p]);
        }
    }

    // ---- epilogue: mean over channels, write planes g*9+dx of [B, 81, H, W] ----
    const float scale = 1.0f / (float)C_;
    float* const op = out + ((size_t)(b * NK) * H_ + gy) * W_ + gx;
#pragma unroll
    for (int dx = 0; dx < ND; ++dx) {
        float4 w4 = make_float4(acc[dx][0] * scale, acc[dx][1] * scale,
                                acc[dx][2] * scale, acc[dx][3] * scale);
        *(float4*)(op + (size_t)(g * ND + dx) * PLANE) = w4;
    }
}

extern "C" void kernel_launch(void* const* d_in, const int* in_sizes, int n_in,
                              void* d_out, int out_size, void* d_ws, size_t ws_size,
                              hipStream_t stream)
{
    const float* feat1 = (const float*)d_in[0];
    const float* feat2 = (const float*)d_in[1];
    float* out = (float*)d_out;

    dim3 grid(NWG);   // 3024 blocks, 1-D; XCD swizzle decoded in-kernel
    dim3 block(NTH);
    corr81_kernel<<<grid, block, 0, stream>>>(feat1, feat2, out);
}

// Round 4
// 354.063 us; speedup vs baseline: 2.2393x; 2.2393x over previous
//
#include <hip/hip_runtime.h>
#include <stdint.h>

namespace {
constexpr int D_  = 4;
constexpr int ND  = 9;     // 2D+1
constexpr int NK  = 81;
constexpr int B_  = 4, C_ = 64, H_ = 192, W_ = 448;

constexpr int TH  = 16;    // output rows per block
constexpr int TXN = 16;    // threads along x
constexpr int PX  = 4;     // pixels per thread along x
constexpr int TW  = TXN * PX;            // 64
constexpr int CCH = 4;                   // channels staged per round
constexpr int HCF = TW + 2 * D_;         // 72 floats per staged row (UNPADDED: gll needs lane-linear LDS)
constexpr int F4R = HCF / 4;             // 18 float4 per row
constexpr int NTH = TH * TXN;            // 256
constexpr int ROUNDS = C_ / CCH;         // 16
constexpr int PLANE  = H_ * W_;          // 86016
constexpr int STGF4  = CCH * TH * F4R;   // 1152 float4 per round
constexpr int RUNS   = STGF4 / 64;       // 18 wave-runs of 64 x 16B
constexpr int BUFF   = STGF4 * 4;        // 4608 floats per buffer

constexpr int NTX = W_ / TW;             // 7
constexpr int NTY = H_ / TH;             // 12
constexpr int NWG = NTX * ND * NTY * B_; // 3024
constexpr int NXCD  = 8;
constexpr int CHUNK = NWG / NXCD;        // 378; 378 % 9 == 0 -> dy-groups never straddle XCDs
static_assert(CHUNK * NXCD == NWG && CHUNK % ND == 0, "bijective, group-aligned swizzle");
}

// zero-initialized .bss page: OOB staging lanes DMA zeros from here (no predication on gll)
__device__ __align__(16) float zpad16[16];

// async global->LDS DMA, 16B per lane; LDS dest = wave-uniform base + lane*16
#define GLLD(gp, lp) __builtin_amdgcn_global_load_lds(                         \
    (const __attribute__((address_space(1))) void*)(gp),                       \
    (__attribute__((address_space(3))) void*)(lp), 16, 0, 0)

__global__ __launch_bounds__(NTH, 2)   // (,2): allow up to 256 VGPRs — LDS caps blocks/CU anyway
void corr81_kernel(const float* __restrict__ f1, const float* __restrict__ f2,
                   float* __restrict__ out)
{
    __shared__ float s2[2 * BUFF];     // 2 x 18432 B = 36864 B -> 4 blocks/CU

    const int tid  = threadIdx.x;
    const int tx   = tid & (TXN - 1);
    const int ty   = tid >> 4;
    const int wave = tid >> 6;

    // ---- T1: bijective XCD-chunked swizzle (dispatch round-robins 8 XCDs) ----
    const int bid = blockIdx.x;
    const int wg  = (bid & (NXCD - 1)) * CHUNK + (bid >> 3);
    const int g   = wg % ND;            // dy fastest -> 9 blocks sharing f1 tile co-run on one XCD
    const int t1  = wg / ND;
    const int tilex = t1 % NTX;
    const int t2  = t1 / NTX;
    const int yt  = t2 % NTY;
    const int b   = t2 / NTY;

    const int x0 = tilex * TW;
    const int y0 = yt * TH;
    const int gx = x0 + tx * PX;
    const int gy = y0 + ty;

    // ---- staging geometry: f4 slot k = tid + 256*j, run = wave + 4*j (wave-uniform LDS base) ----
    const int NRUN = (wave < 2) ? 5 : 4;          // 18 runs over 4 waves
    const float* gptr[5];
    int ginc[5];
#pragma unroll
    for (int j = 0; j < 5; ++j) {
        gptr[j] = zpad16;
        ginc[j] = 0;
        if (j < NRUN) {
            int k   = tid + NTH * j;              // < 1152
            int c   = k / (TH * F4R);             // /288
            int rem = k - c * (TH * F4R);
            int r   = rem / F4R;                  // /18
            int p   = rem - r * F4R;
            int yy  = y0 + g - D_ + r;
            int xx  = x0 - D_ + 4 * p;
            bool ok = (yy >= 0) && (yy < H_) && (xx >= 0) && (xx + 4 <= W_);
            if (ok) {
                gptr[j] = f2 + (((size_t)(b * C_ + c)) * H_ + yy) * W_ + xx;
                ginc[j] = CCH * PLANE;            // advance one round of channels
            }
        }
    }

    float acc[ND][PX];
#pragma unroll
    for (int dx = 0; dx < ND; ++dx)
#pragma unroll
        for (int p = 0; p < PX; ++p) acc[dx][p] = 0.f;

    const float* f1q = f1 + ((size_t)(b * C_) * H_ + gy) * W_ + gx;
    float4 f1v[CCH], f1n[CCH];
#pragma unroll
    for (int c = 0; c < CCH; ++c)
        f1v[c] = *(const float4*)(f1q + (size_t)c * PLANE);

    // ---- prologue: DMA round 0 into buf0 (zero staging VGPRs) ----
#pragma unroll
    for (int j = 0; j < 5; ++j)
        if (j < NRUN)
            GLLD(gptr[j], s2 + (wave + 4 * j) * 256);

#pragma unroll 2
    for (int rr = 0; rr < ROUNDS; ++rr) {
        __syncthreads();   // drains vmcnt: buf[rr&1] DMA complete; prior reads of buf[nxt] done

        // ---- issue next round immediately: DMA f2 -> buf^1, f1 -> regs (land during compute) ----
        if (rr + 1 < ROUNDS) {
            float* lb = s2 + ((rr + 1) & 1) * BUFF;
#pragma unroll
            for (int j = 0; j < 5; ++j)
                if (j < NRUN) {
                    gptr[j] += ginc[j];
                    GLLD(gptr[j], lb + (wave + 4 * j) * 256);
                }
#pragma unroll
            for (int c = 0; c < CCH; ++c)
                f1n[c] = *(const float4*)(f1q + (size_t)((rr + 1) * CCH + c) * PLANE);
        }

        // ---- compute current round: 4 ch x 9 dx x 4 px ----
        const float* sb = s2 + (rr & 1) * BUFF + ty * HCF + 4 * tx;
#pragma unroll
        for (int c = 0; c < CCH; ++c) {
            float a_[PX] = {f1v[c].x, f1v[c].y, f1v[c].z, f1v[c].w};
            const float* rp = sb + c * (TH * HCF);
            float r_[12];
            *(float4*)&r_[0] = *(const float4*)(rp);
            *(float4*)&r_[4] = *(const float4*)(rp + 4);
            *(float4*)&r_[8] = *(const float4*)(rp + 8);
#pragma unroll
            for (int dx = 0; dx < ND; ++dx)
#pragma unroll
                for (int p = 0; p < PX; ++p)
                    acc[dx][p] = fmaf(a_[p], r_[p + dx], acc[dx][p]);
        }

        if (rr + 1 < ROUNDS) {
#pragma unroll
            for (int c = 0; c < CCH; ++c) f1v[c] = f1n[c];
        }
    }

    // ---- epilogue: mean over channels, write planes g*9+dx of [B, 81, H, W] ----
    const float scale = 1.0f / (float)C_;
    float* const op = out + ((size_t)(b * NK) * H_ + gy) * W_ + gx;
#pragma unroll
    for (int dx = 0; dx < ND; ++dx) {
        float4 w4 = make_float4(acc[dx][0] * scale, acc[dx][1] * scale,
                                acc[dx][2] * scale, acc[dx][3] * scale);
        *(float4*)(op + (size_t)(g * ND + dx) * PLANE) = w4;
    }
}

extern "C" void kernel_launch(void* const* d_in, const int* in_sizes, int n_in,
                              void* d_out, int out_size, void* d_ws, size_t ws_size,
                              hipStream_t stream)
{
    const float* feat1 = (const float*)d_in[0];
    const float* feat2 = (const float*)d_in[1];
    float* out = (float*)d_out;

    dim3 grid(NWG);   // 3024 blocks, 1-D; XCD swizzle decoded in-kernel
    dim3 block(NTH);
    corr81_kernel<<<grid, block, 0, stream>>>(feat1, feat2, out);
}

// Round 5
// 352.233 us; speedup vs baseline: 2.2509x; 1.0052x over previous
//
#include <hip/hip_runtime.h>
#include <stdint.h>

namespace {
constexpr int D_  = 4;
constexpr int ND  = 9;     // 2D+1
constexpr int NK  = 81;
constexpr int B_  = 4, C_ = 64, H_ = 192, W_ = 448;

constexpr int TH  = 16;    // output rows per block
constexpr int TXN = 16;    // threads along x
constexpr int PX  = 4;     // pixels per thread along x
constexpr int TW  = TXN * PX;            // 64
constexpr int CCH = 4;                   // channels staged per round
constexpr int HCF = TW + 2 * D_;         // 72 floats per staged row (UNPADDED: gll needs lane-linear LDS)
constexpr int F4R = HCF / 4;             // 18 float4 per row
constexpr int NTH = TH * TXN;            // 256
constexpr int ROUNDS = C_ / CCH;         // 16
constexpr int PLANE  = H_ * W_;          // 86016
constexpr int STGF4  = CCH * TH * F4R;   // 1152 float4 per round
constexpr int BUFF   = STGF4 * 4;        // 4608 floats per buffer
constexpr int RINC   = CCH * PLANE;      // per-round channel advance

constexpr int NTX = W_ / TW;             // 7
constexpr int NTY = H_ / TH;             // 12
constexpr int NWG = NTX * ND * NTY * B_; // 3024
constexpr int NXCD  = 8;
constexpr int CHUNK = NWG / NXCD;        // 378; 378 % 9 == 0 -> dy-groups never straddle XCDs
static_assert(CHUNK * NXCD == NWG && CHUNK % ND == 0, "bijective, group-aligned swizzle");
}

// zero-initialized .bss page: OOB staging lanes DMA zeros from here (no predication on gll)
__device__ __align__(16) float zpad16[16];

// async global->LDS DMA, 16B per lane; LDS dest = wave-uniform base + lane*16
#define GLLD(gp, lp) __builtin_amdgcn_global_load_lds(                         \
    (const __attribute__((address_space(1))) void*)(gp),                       \
    (__attribute__((address_space(3))) void*)(lp), 16, 0, 0)

// NOTE: no waves-per-EU arg. Empirically (rounds 0-4) the 2nd launch_bounds arg
// PINS resident waves (22% at N=2, 44% at N=4) and halves the VGPR cap; with it
// removed, residency floats to the resource limit: LDS 36864B -> 4 blocks/CU.
__global__ __launch_bounds__(NTH)
void corr81_kernel(const float* __restrict__ f1, const float* __restrict__ f2,
                   float* __restrict__ out)
{
    __shared__ float s2[2 * BUFF];     // 2 x 18432 B = 36864 B -> 4 blocks/CU

    const int tid  = threadIdx.x;
    const int tx   = tid & (TXN - 1);
    const int ty   = tid >> 4;
    const int wave = tid >> 6;

    // ---- T1: bijective XCD-chunked swizzle (dispatch round-robins 8 XCDs) ----
    const int bid = blockIdx.x;
    const int wg  = (bid & (NXCD - 1)) * CHUNK + (bid >> 3);
    const int g   = wg % ND;            // dy fastest -> 9 blocks sharing f1 tile co-run on one XCD
    const int t1  = wg / ND;
    const int tilex = t1 % NTX;
    const int t2  = t1 / NTX;
    const int yt  = t2 % NTY;
    const int b   = t2 / NTY;

    const int x0 = tilex * TW;
    const int y0 = yt * TH;
    const int gx = x0 + tx * PX;
    const int gy = y0 + ty;

    // ---- staging geometry: f4 slot k = tid + 256*j, run = wave + 4*j (wave-uniform LDS base) ----
    const int NRUN = (wave < 2) ? 5 : 4;          // 18 runs over 4 waves
    const float* gptr[5];
    bool sok[5];
#pragma unroll
    for (int j = 0; j < 5; ++j) {
        gptr[j] = zpad16;
        sok[j]  = false;
        if (j < NRUN) {
            int k   = tid + NTH * j;              // < 1152
            int c   = k / (TH * F4R);             // /288
            int rem = k - c * (TH * F4R);
            int r   = rem / F4R;                  // /18
            int p   = rem - r * F4R;
            int yy  = y0 + g - D_ + r;
            int xx  = x0 - D_ + 4 * p;
            bool ok = (yy >= 0) && (yy < H_) && (xx >= 0) && (xx + 4 <= W_);
            if (ok) {
                gptr[j] = f2 + (((size_t)(b * C_ + c)) * H_ + yy) * W_ + xx;
                sok[j]  = true;
            }
        }
    }

    float acc[ND][PX];
#pragma unroll
    for (int dx = 0; dx < ND; ++dx)
#pragma unroll
        for (int p = 0; p < PX; ++p) acc[dx][p] = 0.f;

    const float* f1q = f1 + ((size_t)(b * C_) * H_ + gy) * W_ + gx;
    float4 f1v[CCH], f1n[CCH];
#pragma unroll
    for (int c = 0; c < CCH; ++c)
        f1v[c] = *(const float4*)(f1q + (size_t)c * PLANE);

    // ---- prologue: DMA round 0 into buf0 (zero staging VGPRs) ----
#pragma unroll
    for (int j = 0; j < 5; ++j)
        if (j < NRUN)
            GLLD(gptr[j], s2 + (wave + 4 * j) * 256);

#pragma unroll 2
    for (int rr = 0; rr < ROUNDS; ++rr) {
        __syncthreads();   // drains vmcnt: buf[rr&1] DMA complete; prior reads of buf[nxt] done

        // ---- issue next round immediately: DMA f2 -> buf^1, f1 -> regs (land during compute) ----
        if (rr + 1 < ROUNDS) {
            float* lb = s2 + ((rr + 1) & 1) * BUFF;
#pragma unroll
            for (int j = 0; j < 5; ++j)
                if (j < NRUN) {
                    gptr[j] += sok[j] ? RINC : 0;   // OOB lanes stay parked on zpad16
                    GLLD(gptr[j], lb + (wave + 4 * j) * 256);
                }
#pragma unroll
            for (int c = 0; c < CCH; ++c)
                f1n[c] = *(const float4*)(f1q + (size_t)((rr + 1) * CCH + c) * PLANE);
        }

        // ---- compute current round: 4 ch x 9 dx x 4 px ----
        const float* sb = s2 + (rr & 1) * BUFF + ty * HCF + 4 * tx;
#pragma unroll
        for (int c = 0; c < CCH; ++c) {
            float a_[PX] = {f1v[c].x, f1v[c].y, f1v[c].z, f1v[c].w};
            const float* rp = sb + c * (TH * HCF);
            float r_[12];
            *(float4*)&r_[0] = *(const float4*)(rp);
            *(float4*)&r_[4] = *(const float4*)(rp + 4);
            *(float4*)&r_[8] = *(const float4*)(rp + 8);
#pragma unroll
            for (int dx = 0; dx < ND; ++dx)
#pragma unroll
                for (int p = 0; p < PX; ++p)
                    acc[dx][p] = fmaf(a_[p], r_[p + dx], acc[dx][p]);
        }

        if (rr + 1 < ROUNDS) {
#pragma unroll
            for (int c = 0; c < CCH; ++c) f1v[c] = f1n[c];
        }
    }

    // ---- epilogue: mean over channels, write planes g*9+dx of [B, 81, H, W] ----
    const float scale = 1.0f / (float)C_;
    float* const op = out + ((size_t)(b * NK) * H_ + gy) * W_ + gx;
#pragma unroll
    for (int dx = 0; dx < ND; ++dx) {
        float4 w4 = make_float4(acc[dx][0] * scale, acc[dx][1] * scale,
                                acc[dx][2] * scale, acc[dx][3] * scale);
        *(float4*)(op + (size_t)(g * ND + dx) * PLANE) = w4;
    }
}

extern "C" void kernel_launch(void* const* d_in, const int* in_sizes, int n_in,
                              void* d_out, int out_size, void* d_ws, size_t ws_size,
                              hipStream_t stream)
{
    const float* feat1 = (const float*)d_in[0];
    const float* feat2 = (const float*)d_in[1];
    float* out = (float*)d_out;

    dim3 grid(NWG);   // 3024 blocks, 1-D; XCD swizzle decoded in-kernel
    dim3 block(NTH);
    corr81_kernel<<<grid, block, 0, stream>>>(feat1, feat2, out);
}